// Round 1
// baseline (869.783 us; speedup 1.0000x reference)
//
#include <hip/hip_runtime.h>

#define IN_CH 256
#define OUT_CH 512
#define HW 56
#define NPIX (HW * HW)            // 3136
#define WROW (IN_CH * 9)          // 2304
#define NT 10
#define HB 8
#define NDOT (NT * HB)            // 80
#define SLICES 7
#define PIX_PER_SLICE (8 * HW)    // 448
#define SIZE_LIMIT 256
#define EPS 1e-3f

// workspace offsets in 4-byte units
#define Q_OFF      0                          // 256 floats
#define QADDR_OFF  256                        // 10 ints (pad to 32)
#define WADDR_OFF  288                        // 10*512 ints
#define ACTIVE_OFF (WADDR_OFF + NT * OUT_CH)  // 512 ints
#define PSUM_OFF   (ACTIVE_OFF + OUT_CH)      // 512*7 floats
#define PSQ_OFF    (PSUM_OFF + OUT_CH * SLICES)
// total ≈ 13088 * 4B ≈ 52 KB

// ---- 1. global-avg-pool query: q[c] = mean over 56x56 of x[0][c] ----
__global__ void k_query(const float* __restrict__ x, float* __restrict__ wsf) {
    int c = blockIdx.x;
    int tid = threadIdx.x;
    const float* xc = x + c * NPIX;
    float s = 0.f;
    for (int p = tid; p < NPIX; p += 256) s += xc[p];
    __shared__ float red[256];
    red[tid] = s;
    __syncthreads();
    for (int off = 128; off > 0; off >>= 1) {
        if (tid < off) red[tid] += red[tid + off];
        __syncthreads();
    }
    if (tid == 0) wsf[Q_OFF + c] = red[0] / (float)NPIX;
}

// ---- 2. query signatures: 10 tables x 8 bits over q (len 256) ----
__global__ void k_qaddr(const float* __restrict__ rm_q, const float* __restrict__ wsf,
                        int* __restrict__ wsi) {
    __shared__ float qs[IN_CH];
    __shared__ int bits[NDOT];
    int tid = threadIdx.x; // 128 threads
    for (int i = tid; i < IN_CH; i += 128) qs[i] = wsf[Q_OFF + i];
    __syncthreads();
    if (tid < NDOT) {
        const float* r = rm_q + tid * IN_CH;
        float acc = 0.f;
        for (int k = 0; k < IN_CH; k++) acc += r[k] * qs[k];
        bits[tid] = (acc > 0.f) ? 1 : 0;
    }
    __syncthreads();
    if (tid < NT) {
        int a = 0;
        for (int h = 0; h < HB; h++) a |= bits[tid * HB + h] << (7 - h);
        wsi[QADDR_OFF + tid] = a;
    }
}

// ---- 3. weight signatures: per out-channel, 80 dots of length 2304 ----
__global__ void k_waddr(const float* __restrict__ whole_w, const float* __restrict__ rm_w,
                        int* __restrict__ wsi) {
    int o = blockIdx.x;
    int tid = threadIdx.x; // 256
    __shared__ float sW[WROW];
    __shared__ int bits[NDOT];
    for (int i = tid; i < WROW; i += 256) sW[i] = whole_w[o * WROW + i];
    __syncthreads();
    int wid = tid >> 6, lane = tid & 63;
    for (int d = wid; d < NDOT; d += 4) {
        const float* r = rm_w + d * WROW;
        float acc = 0.f;
        for (int k = lane; k < WROW; k += 64) acc += r[k] * sW[k]; // 2304/64 = 36 iters
        for (int m = 32; m > 0; m >>= 1) acc += __shfl_xor(acc, m, 64);
        if (lane == 0) bits[d] = (acc > 0.f) ? 1 : 0;
    }
    __syncthreads();
    if (tid < NT) {
        int a = 0;
        for (int h = 0; h < HB; h++) a |= bits[tid * HB + h] << (7 - h);
        wsi[WADDR_OFF + tid * OUT_CH + o] = a;
    }
}

// ---- 4. histogram + top-k selection (exact jax.lax.top_k tie-break) ----
__global__ void k_select(int* __restrict__ wsi) {
    int o = threadIdx.x; // 512 threads
    __shared__ int hist[OUT_CH];
    __shared__ int qs[NT];
    if (o < NT) qs[o] = wsi[QADDR_OFF + o];
    __syncthreads();
    int h = 0;
    for (int t = 0; t < NT; t++) h += (wsi[WADDR_OFF + t * OUT_CH + o] == qs[t]) ? 1 : 0;
    hist[o] = h;
    __syncthreads();
    // rank in (value desc, index asc) order; selected iff rank < 256 and h > 0
    int rank = 0;
    for (int j = 0; j < OUT_CH; j++) {
        int hj = hist[j];
        rank += (hj > h || (hj == h && j < o)) ? 1 : 0;
    }
    wsi[ACTIVE_OFF + o] = (h > 0 && rank < SIZE_LIMIT) ? 1 : 0;
}

// ---- 5. sparse conv 3x3 pad1 + per-slice BN partial stats ----
__global__ void k_conv(const float* __restrict__ x, const float* __restrict__ whole_w,
                       const int* __restrict__ wsi, float* __restrict__ wsf,
                       float* __restrict__ y) {
    int o = blockIdx.y, slice = blockIdx.x, tid = threadIdx.x;
    if (!wsi[ACTIVE_OFF + o]) return; // uniform per block
    __shared__ float sW[WROW];
    for (int i = tid; i < WROW; i += 256) sW[i] = whole_w[o * WROW + i];
    __syncthreads();
    float lsum = 0.f, lsq = 0.f;
    int p0 = slice * PIX_PER_SLICE;
    for (int p = p0 + tid; p < p0 + PIX_PER_SLICE; p += 256) {
        int oh = p / HW, ow = p % HW;
        float acc = 0.f;
        if (oh >= 1 && oh <= HW - 2 && ow >= 1 && ow <= HW - 2) {
            const float* xb = x + (oh - 1) * HW + (ow - 1);
            for (int c = 0; c < IN_CH; c++) {
                const float* xc = xb + c * NPIX;
                const float* wc = sW + c * 9;
                acc += xc[0] * wc[0] + xc[1] * wc[1] + xc[2] * wc[2];
                acc += xc[HW] * wc[3] + xc[HW + 1] * wc[4] + xc[HW + 2] * wc[5];
                acc += xc[2 * HW] * wc[6] + xc[2 * HW + 1] * wc[7] + xc[2 * HW + 2] * wc[8];
            }
        } else {
            for (int c = 0; c < IN_CH; c++) {
                const float* xc = x + c * NPIX;
                const float* wc = sW + c * 9;
                #pragma unroll
                for (int kh = 0; kh < 3; kh++) {
                    int ih = oh + kh - 1;
                    if (ih < 0 || ih >= HW) continue;
                    #pragma unroll
                    for (int kw = 0; kw < 3; kw++) {
                        int iw = ow + kw - 1;
                        if (iw < 0 || iw >= HW) continue;
                        acc += xc[ih * HW + iw] * wc[kh * 3 + kw];
                    }
                }
            }
        }
        y[o * NPIX + p] = acc;
        lsum += acc;
        lsq += acc * acc;
    }
    __shared__ float rs[256], rq[256];
    rs[tid] = lsum; rq[tid] = lsq;
    __syncthreads();
    for (int off = 128; off > 0; off >>= 1) {
        if (tid < off) { rs[tid] += rs[tid + off]; rq[tid] += rq[tid + off]; }
        __syncthreads();
    }
    if (tid == 0) {
        wsf[PSUM_OFF + o * SLICES + slice] = rs[0];
        wsf[PSQ_OFF + o * SLICES + slice] = rq[0];
    }
}

// ---- 6. batch-norm (train-mode batch stats) + ReLU, in place on d_out ----
__global__ void k_bn(const float* __restrict__ wsf, const int* __restrict__ wsi,
                     const float* __restrict__ gamma, const float* __restrict__ beta,
                     float* __restrict__ y) {
    int o = blockIdx.x, tid = threadIdx.x;
    if (!wsi[ACTIVE_OFF + o]) {
        for (int p = tid; p < NPIX; p += 256) y[o * NPIX + p] = 0.f;
        return;
    }
    float s = 0.f, q = 0.f;
    for (int i = 0; i < SLICES; i++) {
        s += wsf[PSUM_OFF + o * SLICES + i];
        q += wsf[PSQ_OFF + o * SLICES + i];
    }
    float mean = s / (float)NPIX;
    float var = q / (float)NPIX - mean * mean;
    float inv = 1.0f / sqrtf(var + EPS);
    float g = gamma[o], b = beta[o];
    for (int p = tid; p < NPIX; p += 256) {
        float v = (y[o * NPIX + p] - mean) * inv * g + b;
        y[o * NPIX + p] = (v > 0.f) ? v : 0.f;
    }
}

extern "C" void kernel_launch(void* const* d_in, const int* in_sizes, int n_in,
                              void* d_out, int out_size, void* d_ws, size_t ws_size,
                              hipStream_t stream) {
    const float* x       = (const float*)d_in[0];
    const float* whole_w = (const float*)d_in[1];
    const float* rm_w    = (const float*)d_in[2];
    const float* rm_q    = (const float*)d_in[3];
    const float* gamma   = (const float*)d_in[4];
    const float* beta    = (const float*)d_in[5];
    float* out = (float*)d_out;
    float* wsf = (float*)d_ws;
    int*   wsi = (int*)d_ws;

    k_query<<<256, 256, 0, stream>>>(x, wsf);
    k_qaddr<<<1, 128, 0, stream>>>(rm_q, wsf, wsi);
    k_waddr<<<OUT_CH, 256, 0, stream>>>(whole_w, rm_w, wsi);
    k_select<<<1, OUT_CH, 0, stream>>>(wsi);
    k_conv<<<dim3(SLICES, OUT_CH), 256, 0, stream>>>(x, whole_w, wsi, wsf, out);
    k_bn<<<OUT_CH, 256, 0, stream>>>(wsf, wsi, gamma, beta, out);
}

// Round 2
// 256.842 us; speedup vs baseline: 3.3865x; 3.3865x over previous
//
#include <hip/hip_runtime.h>

#define IN_CH 256
#define OUT_CH 512
#define HW 56
#define NPIX (HW * HW)            // 3136
#define WROW (IN_CH * 9)          // 2304
#define NT 10
#define HB 8
#define NDOT (NT * HB)            // 80
#define SIZE_LIMIT 256
#define EPS 1e-3f

// conv tiling
#define OTILE 4
#define PTILE 256
#define PTILES 13                 // ceil(3136/256)
#define OTILES (SIZE_LIMIT / OTILE) // 64 worst-case
#define KSPLIT 2
#define KCH (IN_CH / KSPLIT)      // 128

// workspace offsets (4-byte units)
#define Q_OFF       0                           // 256 f
#define QADDR_OFF   256                         // 10 i
#define WADDR_OFF   288                         // 10*512 i
#define ACTIVE_OFF  (WADDR_OFF + NT * OUT_CH)   // 512 i
#define NACT_OFF    (ACTIVE_OFF + OUT_CH)       // 1 i
#define COMPACT_OFF (NACT_OFF + 32)             // 512 i

// ---- 1. global-avg-pool query ----
__global__ void k_query(const float* __restrict__ x, float* __restrict__ wsf) {
    int c = blockIdx.x;
    int tid = threadIdx.x;
    const float* xc = x + c * NPIX;
    float s = 0.f;
    for (int p = tid; p < NPIX; p += 256) s += xc[p];
    __shared__ float red[256];
    red[tid] = s;
    __syncthreads();
    for (int off = 128; off > 0; off >>= 1) {
        if (tid < off) red[tid] += red[tid + off];
        __syncthreads();
    }
    if (tid == 0) wsf[Q_OFF + c] = red[0] / (float)NPIX;
}

// ---- 2. query signatures ----
__global__ void k_qaddr(const float* __restrict__ rm_q, const float* __restrict__ wsf,
                        int* __restrict__ wsi) {
    __shared__ float qs[IN_CH];
    __shared__ int bits[NDOT];
    int tid = threadIdx.x; // 128
    for (int i = tid; i < IN_CH; i += 128) qs[i] = wsf[Q_OFF + i];
    __syncthreads();
    if (tid < NDOT) {
        const float* r = rm_q + tid * IN_CH;
        float acc = 0.f;
        for (int k = 0; k < IN_CH; k++) acc += r[k] * qs[k];
        bits[tid] = (acc > 0.f) ? 1 : 0;
    }
    __syncthreads();
    if (tid < NT) {
        int a = 0;
        for (int h = 0; h < HB; h++) a |= bits[tid * HB + h] << (7 - h);
        wsi[QADDR_OFF + tid] = a;
    }
}

// ---- 3. weight signatures: 4 channels/block, stream rm_w once per block ----
__global__ __launch_bounds__(256) void k_waddr(const float* __restrict__ whole_w,
                                               const float* __restrict__ rm_w,
                                               int* __restrict__ wsi) {
    int o0 = blockIdx.x * 4;  // 128 blocks
    int tid = threadIdx.x;    // 256
    __shared__ float sW[4][WROW];
    __shared__ int bits[NDOT][4];
    for (int i = tid; i < 4 * WROW; i += 256)
        sW[i / WROW][i % WROW] = whole_w[o0 * WROW + i];
    __syncthreads();
    int wid = tid >> 6, lane = tid & 63;
    for (int d = wid; d < NDOT; d += 4) {   // 20 dots per wave
        const float* r = rm_w + d * WROW;
        float a0 = 0.f, a1 = 0.f, a2 = 0.f, a3 = 0.f;
        for (int k = lane; k < WROW; k += 64) {  // 36 iters
            float rv = r[k];
            a0 = fmaf(rv, sW[0][k], a0);
            a1 = fmaf(rv, sW[1][k], a1);
            a2 = fmaf(rv, sW[2][k], a2);
            a3 = fmaf(rv, sW[3][k], a3);
        }
        for (int m = 32; m > 0; m >>= 1) {
            a0 += __shfl_xor(a0, m, 64);
            a1 += __shfl_xor(a1, m, 64);
            a2 += __shfl_xor(a2, m, 64);
            a3 += __shfl_xor(a3, m, 64);
        }
        if (lane == 0) {
            bits[d][0] = (a0 > 0.f) ? 1 : 0;
            bits[d][1] = (a1 > 0.f) ? 1 : 0;
            bits[d][2] = (a2 > 0.f) ? 1 : 0;
            bits[d][3] = (a3 > 0.f) ? 1 : 0;
        }
    }
    __syncthreads();
    if (tid < NT * 4) {
        int t = tid >> 2, j = tid & 3;
        int a = 0;
        for (int h = 0; h < HB; h++) a |= bits[t * HB + h][j] << (7 - h);
        wsi[WADDR_OFF + t * OUT_CH + o0 + j] = a;
    }
}

// ---- 4. histogram + top-k + compaction ----
__global__ void k_select(int* __restrict__ wsi) {
    int o = threadIdx.x; // 512
    __shared__ int hist[OUT_CH];
    __shared__ int sel[OUT_CH];
    __shared__ int qs[NT];
    if (o < NT) qs[o] = wsi[QADDR_OFF + o];
    __syncthreads();
    int h = 0;
    for (int t = 0; t < NT; t++) h += (wsi[WADDR_OFF + t * OUT_CH + o] == qs[t]) ? 1 : 0;
    hist[o] = h;
    __syncthreads();
    int rank = 0;
    for (int j = 0; j < OUT_CH; j++) {
        int hj = hist[j];
        rank += (hj > h || (hj == h && j < o)) ? 1 : 0;
    }
    int s = (h > 0 && rank < SIZE_LIMIT) ? 1 : 0;
    sel[o] = s;
    wsi[ACTIVE_OFF + o] = s;
    __syncthreads();
    if (s) {
        int pos = 0;
        for (int j = 0; j < o; j++) pos += sel[j];
        wsi[COMPACT_OFF + pos] = o;
    }
    if (o == 0) {
        int c = 0;
        for (int j = 0; j < OUT_CH; j++) c += sel[j];
        wsi[NACT_OFF] = c;
    }
}

// ---- 5a. zero d_out (conv accumulates atomically) ----
__global__ void k_zero(float4* __restrict__ y4) {
    int i = blockIdx.x * 256 + threadIdx.x;
    if (i < OUT_CH * NPIX / 4) y4[i] = make_float4(0.f, 0.f, 0.f, 0.f);
}

// ---- 5b. sparse conv: 4 channels x 256 pixels x 128 in-ch per block ----
__global__ __launch_bounds__(256) void k_conv2(const float* __restrict__ x,
                                               const float* __restrict__ whole_w,
                                               const int* __restrict__ wsi,
                                               float* __restrict__ y) {
    int nact = wsi[NACT_OFF];
    int slot0 = blockIdx.y * OTILE;
    if (slot0 >= nact) return;
    int tid = threadIdx.x;
    int p = blockIdx.x * PTILE + tid;
    bool pv = p < NPIX;
    int pc = pv ? p : 0;
    int oh = pc / HW, ow = pc - oh * HW;

    // 9 tap offsets (clamped) + masks
    int offs[9];
    bool msk[9];
    #pragma unroll
    for (int kh = -1; kh <= 1; kh++) {
        #pragma unroll
        for (int kw = -1; kw <= 1; kw++) {
            int t = (kh + 1) * 3 + (kw + 1);
            bool m = (oh + kh >= 0) && (oh + kh < HW) && (ow + kw >= 0) && (ow + kw < HW);
            msk[t] = m;
            offs[t] = m ? kh * HW + kw : 0;
        }
    }

    // channel slots -> scalar weight bases
    int oj[OTILE];
    const float* wb[OTILE];
    #pragma unroll
    for (int j = 0; j < OTILE; j++) {
        int s = slot0 + j;
        int o = (s < nact) ? wsi[COMPACT_OFF + s] : wsi[COMPACT_OFF + slot0];
        oj[j] = (s < nact) ? o : -1;
        int ou = __builtin_amdgcn_readfirstlane(o);
        wb[j] = whole_w + (size_t)ou * WROW + blockIdx.z * (KCH * 9);
    }

    const float* xb = x + blockIdx.z * (KCH * NPIX) + pc;
    float a0 = 0.f, a1 = 0.f, a2 = 0.f, a3 = 0.f;
    for (int c = 0; c < KCH; ++c) {
        const float* xc = xb + c * NPIX;
        float xv[9];
        #pragma unroll
        for (int t = 0; t < 9; t++) xv[t] = msk[t] ? xc[offs[t]] : 0.f;
        #pragma unroll
        for (int t = 0; t < 9; t++) {
            int wi = c * 9 + t;
            a0 = fmaf(xv[t], wb[0][wi], a0);
            a1 = fmaf(xv[t], wb[1][wi], a1);
            a2 = fmaf(xv[t], wb[2][wi], a2);
            a3 = fmaf(xv[t], wb[3][wi], a3);
        }
    }
    if (pv) {
        if (oj[0] >= 0) atomicAdd(&y[oj[0] * NPIX + p], a0);
        if (oj[1] >= 0) atomicAdd(&y[oj[1] * NPIX + p], a1);
        if (oj[2] >= 0) atomicAdd(&y[oj[2] * NPIX + p], a2);
        if (oj[3] >= 0) atomicAdd(&y[oj[3] * NPIX + p], a3);
    }
}

// ---- 6. BN (train-mode batch stats) + ReLU ----
__global__ void k_bn(const int* __restrict__ wsi,
                     const float* __restrict__ gamma, const float* __restrict__ beta,
                     float* __restrict__ y) {
    int o = blockIdx.x, tid = threadIdx.x;
    if (!wsi[ACTIVE_OFF + o]) return; // y already zeroed by k_zero
    float s = 0.f, q = 0.f;
    for (int p = tid; p < NPIX; p += 256) {
        float v = y[o * NPIX + p];
        s += v;
        q += v * v;
    }
    __shared__ float rs[256], rq[256];
    rs[tid] = s; rq[tid] = q;
    __syncthreads();
    for (int off = 128; off > 0; off >>= 1) {
        if (tid < off) { rs[tid] += rs[tid + off]; rq[tid] += rq[tid + off]; }
        __syncthreads();
    }
    float mean = rs[0] / (float)NPIX;
    float var = rq[0] / (float)NPIX - mean * mean;
    float inv = 1.0f / sqrtf(var + EPS);
    float g = gamma[o], b = beta[o];
    for (int p = tid; p < NPIX; p += 256) {
        float v = (y[o * NPIX + p] - mean) * inv * g + b;
        y[o * NPIX + p] = (v > 0.f) ? v : 0.f;
    }
}

extern "C" void kernel_launch(void* const* d_in, const int* in_sizes, int n_in,
                              void* d_out, int out_size, void* d_ws, size_t ws_size,
                              hipStream_t stream) {
    const float* x       = (const float*)d_in[0];
    const float* whole_w = (const float*)d_in[1];
    const float* rm_w    = (const float*)d_in[2];
    const float* rm_q    = (const float*)d_in[3];
    const float* gamma   = (const float*)d_in[4];
    const float* beta    = (const float*)d_in[5];
    float* out = (float*)d_out;
    float* wsf = (float*)d_ws;
    int*   wsi = (int*)d_ws;

    k_query<<<256, 256, 0, stream>>>(x, wsf);
    k_qaddr<<<1, 128, 0, stream>>>(rm_q, wsf, wsi);
    k_waddr<<<OUT_CH / 4, 256, 0, stream>>>(whole_w, rm_w, wsi);
    k_select<<<1, OUT_CH, 0, stream>>>(wsi);
    k_zero<<<(OUT_CH * NPIX / 4 + 255) / 256, 256, 0, stream>>>((float4*)out);
    k_conv2<<<dim3(PTILES, OTILES, KSPLIT), 256, 0, stream>>>(x, whole_w, wsi, out);
    k_bn<<<OUT_CH, 256, 0, stream>>>(wsi, gamma, beta, out);
}

// Round 3
// 82.315 us; speedup vs baseline: 10.5665x; 3.1202x over previous
//
#include <hip/hip_runtime.h>

#define IN_CH 256
#define OUT_CH 512
#define HW 56
#define NPIX (HW * HW)            // 3136
#define WROW (IN_CH * 9)          // 2304
#define NT 10
#define HB 8
#define NDOT (NT * HB)            // 80
#define SIZE_LIMIT 256
#define EPS 1e-3f

// waddr tiling
#define WOTILE 2
#define DG 10
#define DOTS_PER_BLK (NDOT / DG)  // 8 -> 2 dots per wave

// conv tiling
#define OTILE 4
#define PTILE 256
#define PTILES 13                 // ceil(3136/256)
#define OTILES (SIZE_LIMIT / OTILE) // 64 worst-case
#define KSPLIT 8
#define KCH (IN_CH / KSPLIT)      // 32

// workspace offsets (4-byte units)
#define Q_OFF       0                           // 256 f
#define QADDR_OFF   256                         // 10 i
#define WADDR_OFF   288                         // 10*512 i (atomicOr targets)
#define ACTIVE_OFF  (WADDR_OFF + NT * OUT_CH)   // 512 i
#define NACT_OFF    (ACTIVE_OFF + OUT_CH)       // 1 i
#define COMPACT_OFF (NACT_OFF + 32)             // 512 i

// ---- 1. global-avg-pool query ----
__global__ void k_query(const float* __restrict__ x, float* __restrict__ wsf) {
    int c = blockIdx.x;
    int tid = threadIdx.x;
    const float* xc = x + c * NPIX;
    float s = 0.f;
    for (int p = tid; p < NPIX; p += 256) s += xc[p];
    __shared__ float red[256];
    red[tid] = s;
    __syncthreads();
    for (int off = 128; off > 0; off >>= 1) {
        if (tid < off) red[tid] += red[tid + off];
        __syncthreads();
    }
    if (tid == 0) wsf[Q_OFF + c] = red[0] / (float)NPIX;
}

// ---- 2. query signatures + zero the weight-signature words ----
__global__ void k_qaddr(const float* __restrict__ rm_q, const float* __restrict__ wsf,
                        int* __restrict__ wsi) {
    int tid = threadIdx.x; // 128
    for (int i = tid; i < NT * OUT_CH; i += 128) wsi[WADDR_OFF + i] = 0;
    __shared__ float qs[IN_CH];
    __shared__ int bits[NDOT];
    for (int i = tid; i < IN_CH; i += 128) qs[i] = wsf[Q_OFF + i];
    __syncthreads();
    if (tid < NDOT) {
        const float* r = rm_q + tid * IN_CH;
        float acc = 0.f;
        for (int k = 0; k < IN_CH; k++) acc += r[k] * qs[k];
        bits[tid] = (acc > 0.f) ? 1 : 0;
    }
    __syncthreads();
    if (tid < NT) {
        int a = 0;
        for (int h = 0; h < HB; h++) a |= bits[tid * HB + h] << (7 - h);
        wsi[QADDR_OFF + tid] = a;
    }
}

// ---- 3. weight signatures: 2 channels x 8 dots per block, float4, atomicOr ----
__global__ __launch_bounds__(256) void k_waddr(const float* __restrict__ whole_w,
                                               const float* __restrict__ rm_w,
                                               int* __restrict__ wsi) {
    int o0 = blockIdx.x * WOTILE;
    int dg = blockIdx.y;
    int tid = threadIdx.x;
    __shared__ float4 sW4[WOTILE][WROW / 4];  // 2 x 576 float4 = 18.4 KB
    const float4* w4 = (const float4*)(whole_w + (size_t)o0 * WROW);
    for (int i = tid; i < WOTILE * (WROW / 4); i += 256)
        sW4[i / (WROW / 4)][i % (WROW / 4)] = w4[i];
    __syncthreads();
    int wid = tid >> 6, lane = tid & 63;
    int d0 = dg * DOTS_PER_BLK + wid * 2;  // 2 dots per wave
    const float4* r0 = (const float4*)(rm_w + (size_t)d0 * WROW);
    const float4* r1 = (const float4*)(rm_w + (size_t)(d0 + 1) * WROW);
    float a00 = 0.f, a01 = 0.f, a10 = 0.f, a11 = 0.f;
    for (int i = lane; i < WROW / 4; i += 64) {  // 9 iters
        float4 v0 = r0[i], v1 = r1[i];
        float4 w0 = sW4[0][i], w1 = sW4[1][i];
        a00 += v0.x * w0.x + v0.y * w0.y + v0.z * w0.z + v0.w * w0.w;
        a01 += v0.x * w1.x + v0.y * w1.y + v0.z * w1.z + v0.w * w1.w;
        a10 += v1.x * w0.x + v1.y * w0.y + v1.z * w0.z + v1.w * w0.w;
        a11 += v1.x * w1.x + v1.y * w1.y + v1.z * w1.z + v1.w * w1.w;
    }
    for (int m = 32; m > 0; m >>= 1) {
        a00 += __shfl_xor(a00, m, 64);
        a01 += __shfl_xor(a01, m, 64);
        a10 += __shfl_xor(a10, m, 64);
        a11 += __shfl_xor(a11, m, 64);
    }
    if (lane == 0) {
        int t0 = d0 / HB, h0 = d0 % HB;
        int t1 = (d0 + 1) / HB, h1 = (d0 + 1) % HB;
        if (a00 > 0.f) atomicOr(&wsi[WADDR_OFF + t0 * OUT_CH + o0],     1 << (7 - h0));
        if (a01 > 0.f) atomicOr(&wsi[WADDR_OFF + t0 * OUT_CH + o0 + 1], 1 << (7 - h0));
        if (a10 > 0.f) atomicOr(&wsi[WADDR_OFF + t1 * OUT_CH + o0],     1 << (7 - h1));
        if (a11 > 0.f) atomicOr(&wsi[WADDR_OFF + t1 * OUT_CH + o0 + 1], 1 << (7 - h1));
    }
}

// ---- 4. histogram + top-k + compaction ----
__global__ void k_select(int* __restrict__ wsi) {
    int o = threadIdx.x; // 512
    __shared__ int hist[OUT_CH];
    __shared__ int sel[OUT_CH];
    __shared__ int qs[NT];
    if (o < NT) qs[o] = wsi[QADDR_OFF + o];
    __syncthreads();
    int h = 0;
    for (int t = 0; t < NT; t++) h += (wsi[WADDR_OFF + t * OUT_CH + o] == qs[t]) ? 1 : 0;
    hist[o] = h;
    __syncthreads();
    int rank = 0;
    for (int j = 0; j < OUT_CH; j++) {
        int hj = hist[j];
        rank += (hj > h || (hj == h && j < o)) ? 1 : 0;
    }
    int s = (h > 0 && rank < SIZE_LIMIT) ? 1 : 0;
    sel[o] = s;
    wsi[ACTIVE_OFF + o] = s;
    __syncthreads();
    if (s) {
        int pos = 0;
        for (int j = 0; j < o; j++) pos += sel[j];
        wsi[COMPACT_OFF + pos] = o;
    }
    if (o == 0) {
        int c = 0;
        for (int j = 0; j < OUT_CH; j++) c += sel[j];
        wsi[NACT_OFF] = c;
    }
}

// ---- 5a. zero d_out (conv accumulates atomically) ----
__global__ void k_zero(float4* __restrict__ y4) {
    int i = blockIdx.x * 256 + threadIdx.x;
    if (i < OUT_CH * NPIX / 4) y4[i] = make_float4(0.f, 0.f, 0.f, 0.f);
}

// ---- 5b. sparse conv: 4 channels x 256 pixels x 32 in-ch per block ----
__global__ __launch_bounds__(256) void k_conv2(const float* __restrict__ x,
                                               const float* __restrict__ whole_w,
                                               const int* __restrict__ wsi,
                                               float* __restrict__ y) {
    int nact = wsi[NACT_OFF];
    int slot0 = blockIdx.y * OTILE;
    if (slot0 >= nact) return;
    int tid = threadIdx.x;
    int p = blockIdx.x * PTILE + tid;
    bool pv = p < NPIX;
    int pc = pv ? p : 0;
    int oh = pc / HW, ow = pc - oh * HW;

    int offs[9];
    bool msk[9];
    #pragma unroll
    for (int kh = -1; kh <= 1; kh++) {
        #pragma unroll
        for (int kw = -1; kw <= 1; kw++) {
            int t = (kh + 1) * 3 + (kw + 1);
            bool m = (oh + kh >= 0) && (oh + kh < HW) && (ow + kw >= 0) && (ow + kw < HW);
            msk[t] = m;
            offs[t] = m ? kh * HW + kw : 0;
        }
    }

    int oj[OTILE];
    const float* wb[OTILE];
    #pragma unroll
    for (int j = 0; j < OTILE; j++) {
        int s = slot0 + j;
        int o = (s < nact) ? wsi[COMPACT_OFF + s] : wsi[COMPACT_OFF + slot0];
        oj[j] = (s < nact) ? o : -1;
        int ou = __builtin_amdgcn_readfirstlane(o);
        wb[j] = whole_w + (size_t)ou * WROW + blockIdx.z * (KCH * 9);
    }

    const float* xb = x + blockIdx.z * (KCH * NPIX) + pc;
    float a0 = 0.f, a1 = 0.f, a2 = 0.f, a3 = 0.f;
    for (int c = 0; c < KCH; ++c) {
        const float* xc = xb + c * NPIX;
        float xv[9];
        #pragma unroll
        for (int t = 0; t < 9; t++) xv[t] = msk[t] ? xc[offs[t]] : 0.f;
        #pragma unroll
        for (int t = 0; t < 9; t++) {
            int wi = c * 9 + t;
            a0 = fmaf(xv[t], wb[0][wi], a0);
            a1 = fmaf(xv[t], wb[1][wi], a1);
            a2 = fmaf(xv[t], wb[2][wi], a2);
            a3 = fmaf(xv[t], wb[3][wi], a3);
        }
    }
    if (pv) {
        if (oj[0] >= 0) atomicAdd(&y[oj[0] * NPIX + p], a0);
        if (oj[1] >= 0) atomicAdd(&y[oj[1] * NPIX + p], a1);
        if (oj[2] >= 0) atomicAdd(&y[oj[2] * NPIX + p], a2);
        if (oj[3] >= 0) atomicAdd(&y[oj[3] * NPIX + p], a3);
    }
}

// ---- 6. BN (train-mode batch stats) + ReLU ----
__global__ void k_bn(const int* __restrict__ wsi,
                     const float* __restrict__ gamma, const float* __restrict__ beta,
                     float* __restrict__ y) {
    int o = blockIdx.x, tid = threadIdx.x;
    if (!wsi[ACTIVE_OFF + o]) return; // y already zeroed by k_zero
    float s = 0.f, q = 0.f;
    for (int p = tid; p < NPIX; p += 256) {
        float v = y[o * NPIX + p];
        s += v;
        q += v * v;
    }
    __shared__ float rs[256], rq[256];
    rs[tid] = s; rq[tid] = q;
    __syncthreads();
    for (int off = 128; off > 0; off >>= 1) {
        if (tid < off) { rs[tid] += rs[tid + off]; rq[tid] += rq[tid + off]; }
        __syncthreads();
    }
    float mean = rs[0] / (float)NPIX;
    float var = rq[0] / (float)NPIX - mean * mean;
    float inv = 1.0f / sqrtf(var + EPS);
    float g = gamma[o], b = beta[o];
    for (int p = tid; p < NPIX; p += 256) {
        float v = (y[o * NPIX + p] - mean) * inv * g + b;
        y[o * NPIX + p] = (v > 0.f) ? v : 0.f;
    }
}

extern "C" void kernel_launch(void* const* d_in, const int* in_sizes, int n_in,
                              void* d_out, int out_size, void* d_ws, size_t ws_size,
                              hipStream_t stream) {
    const float* x       = (const float*)d_in[0];
    const float* whole_w = (const float*)d_in[1];
    const float* rm_w    = (const float*)d_in[2];
    const float* rm_q    = (const float*)d_in[3];
    const float* gamma   = (const float*)d_in[4];
    const float* beta    = (const float*)d_in[5];
    float* out = (float*)d_out;
    float* wsf = (float*)d_ws;
    int*   wsi = (int*)d_ws;

    k_query<<<256, 256, 0, stream>>>(x, wsf);
    k_qaddr<<<1, 128, 0, stream>>>(rm_q, wsf, wsi);
    k_waddr<<<dim3(OUT_CH / WOTILE, DG), 256, 0, stream>>>(whole_w, rm_w, wsi);
    k_select<<<1, OUT_CH, 0, stream>>>(wsi);
    k_zero<<<(OUT_CH * NPIX / 4 + 255) / 256, 256, 0, stream>>>((float4*)out);
    k_conv2<<<dim3(PTILES, OTILES, KSPLIT), 256, 0, stream>>>(x, whole_w, wsi, out);
    k_bn<<<OUT_CH, 256, 0, stream>>>(wsi, gamma, beta, out);
}